// Round 2
// baseline (423.734 us; speedup 1.0000x reference)
//
#include <hip/hip_runtime.h>
#include <stdint.h>

// ---------------------------------------------------------------------------
// MultiHeadAdaptiveChebyshevLayer, round 4 (= round 3 resubmit + VGPR hedge).
// R3 failed with an infra-level "container failed twice" (no compile error,
// no test output) — kernel audited clean (bounds/alignment/LDS/launch).
//
// Design: single fused kernel, NO workspace (the harness's 1 GiB ws
// poison-fill was 165.7 us/iter = 52% of R0's 320 us).  Raw fp32 weights
// read straight from L2; each block processes TWO batch rows so every
// kern/poly/gamma/beta load is shared between rows (halves per-row weight
// traffic).  Chebyshev recurrence kept as a rotating 3-register window
// interleaved with the weight FMAs (VGPR hedge vs R3's T[8] arrays).
//
// Ownership (per row): thread t owns features f = c*4096 + t*4 + {0..3},
// c = 0..15.  f = p*8 + k with p = c*512 + (t>>1), k = (t&1)*4 + d, so the
// kern float4 for (p, m, k0..3) is at kern + p*64 + m*8 + k0 — lane pairs
// read contiguous 32 B, L1/L2-served after first touch.
// ---------------------------------------------------------------------------

#define LN_EPS 1e-5f

typedef float vfloat4 __attribute__((ext_vector_type(4)));

__device__ __forceinline__ unsigned bf16_rne(float f) {
    unsigned u = __float_as_uint(f);
    unsigned r = u + 0x7fffu + ((u >> 16) & 1u);
    return r >> 16;
}
__device__ __forceinline__ float bf_lo(unsigned u) { return __uint_as_float(u << 16); }
__device__ __forceinline__ float bf_hi(unsigned u) { return __uint_as_float(u & 0xffff0000u); }

__global__ __launch_bounds__(1024, 4) void cheb_ln_fused(
    const float* __restrict__ x, const float* __restrict__ scale,
    const float* __restrict__ poly, const float* __restrict__ kern,
    const float* __restrict__ gamma, const float* __restrict__ beta,
    float* __restrict__ out) {
    __shared__ float xs[2][8192];
    __shared__ float red[64];
    const int r0 = blockIdx.x << 1;
    const int t = threadIdx.x;
    const int w = t >> 6, l = t & 63;
    const int phalf = t >> 1;        // p = c*512 + phalf
    const int k0 = (t & 1) << 2;     // k offset: 0 or 4

    // Stage xs[r][h*1024+i] = x[r][i] * scale[h][i]; scale loaded once for
    // both rows.  Coalesced; readback is 2-way same-address (free).
    float xv0 = x[(size_t)r0 * 1024 + t];
    float xv1 = x[(size_t)(r0 + 1) * 1024 + t];
#pragma unroll
    for (int h = 0; h < 8; ++h) {
        float s = scale[h * 1024 + t];
        xs[0][h * 1024 + t] = xv0 * s;
        xs[1][h * 1024 + t] = xv1 * s;
    }
    __syncthreads();

    unsigned y0[32], y1[32];         // 2 rows x 64 y-values as packed bf16
    float sum0 = 0.f, sq0 = 0.f, sum1 = 0.f, sq1 = 0.f;

#pragma unroll
    for (int c = 0; c < 16; ++c) {
        const int p = c * 512 + phalf;
        const float4* kp = (const float4*)(kern + (size_t)p * 64 + k0);
        float4 pw = *(const float4*)(poly + (size_t)p * 8 + k0);

        float va = xs[0][c * 512 + phalf];
        float vb = xs[1][c * 512 + phalf];
        float va2 = va + va, vb2 = vb + vb;

        // m = 0 (T0 == 1): accumulator init from the first weight quad.
        float a0, a1, a2, a3, b0, b1, b2, b3;
        {
            float4 w0 = kp[0];
            a0 = w0.x; a1 = w0.y; a2 = w0.z; a3 = w0.w;
            b0 = w0.x; b1 = w0.y; b2 = w0.z; b3 = w0.w;
        }
        // m = 1..7: rotating 3-deep Chebyshev window, each weight quad
        // consumed immediately by BOTH rows (min live set, fits 128 VGPR).
        float tam2 = 1.f, tam1 = va;   // T_{m-2}, T_{m-1} for row a
        float tbm2 = 1.f, tbm1 = vb;
#pragma unroll
        for (int m = 1; m < 8; ++m) {
            float4 wm = kp[m * 2];   // float4 stride 2 == 8 floats per m
            a0 = fmaf(tam1, wm.x, a0); b0 = fmaf(tbm1, wm.x, b0);
            a1 = fmaf(tam1, wm.y, a1); b1 = fmaf(tbm1, wm.y, b1);
            a2 = fmaf(tam1, wm.z, a2); b2 = fmaf(tbm1, wm.z, b2);
            a3 = fmaf(tam1, wm.w, a3); b3 = fmaf(tbm1, wm.w, b3);
            float tan_ = fmaf(va2, tam1, -tam2);  // T_m -> next iter's T_{m-1}
            float tbn_ = fmaf(vb2, tbm1, -tbm2);
            tam2 = tam1; tam1 = tan_;
            tbm2 = tbm1; tbm1 = tbn_;
        }

        a0 *= pw.x; a1 *= pw.y; a2 *= pw.z; a3 *= pw.w;
        b0 *= pw.x; b1 *= pw.y; b2 *= pw.z; b3 *= pw.w;

        sum0 += (a0 + a1) + (a2 + a3);
        sq0 = fmaf(a0, a0, sq0); sq0 = fmaf(a1, a1, sq0);
        sq0 = fmaf(a2, a2, sq0); sq0 = fmaf(a3, a3, sq0);
        y0[c * 2 + 0] = bf16_rne(a0) | (bf16_rne(a1) << 16);
        y0[c * 2 + 1] = bf16_rne(a2) | (bf16_rne(a3) << 16);

        sum1 += (b0 + b1) + (b2 + b3);
        sq1 = fmaf(b0, b0, sq1); sq1 = fmaf(b1, b1, sq1);
        sq1 = fmaf(b2, b2, sq1); sq1 = fmaf(b3, b3, sq1);
        y1[c * 2 + 0] = bf16_rne(b0) | (bf16_rne(b1) << 16);
        y1[c * 2 + 1] = bf16_rne(b2) | (bf16_rne(b3) << 16);
    }

    // Wave reduce (64 lanes), then cross-wave via LDS.
#pragma unroll
    for (int off = 32; off; off >>= 1) {
        sum0 += __shfl_down(sum0, off, 64);
        sq0  += __shfl_down(sq0,  off, 64);
        sum1 += __shfl_down(sum1, off, 64);
        sq1  += __shfl_down(sq1,  off, 64);
    }
    if (l == 0) {
        red[w * 4 + 0] = sum0; red[w * 4 + 1] = sq0;
        red[w * 4 + 2] = sum1; red[w * 4 + 3] = sq1;
    }
    __syncthreads();
    float S0 = 0.f, Q0 = 0.f, S1 = 0.f, Q1 = 0.f;
#pragma unroll
    for (int q = 0; q < 16; ++q) {
        S0 += red[q * 4 + 0]; Q0 += red[q * 4 + 1];
        S1 += red[q * 4 + 2]; Q1 += red[q * 4 + 3];
    }
    const float inv = 1.f / 65536.f;
    float mu0 = S0 * inv, mu1 = S1 * inv;
    float rs0 = rsqrtf(fmaf(-mu0, mu0, Q0 * inv) + LN_EPS);
    float rs1 = rsqrtf(fmaf(-mu1, mu1, Q1 * inv) + LN_EPS);

    // Epilogue: gamma/beta loaded once, applied to both rows; NT stores.
    float* o0 = out + (size_t)r0 * 65536;
    float* o1 = o0 + 65536;
#pragma unroll
    for (int c = 0; c < 16; ++c) {
        float4 g = *(const float4*)(gamma + c * 4096 + t * 4);
        float4 b = *(const float4*)(beta  + c * 4096 + t * 4);
        unsigned u0 = y0[c * 2 + 0], u1 = y0[c * 2 + 1];
        vfloat4 oA;
        oA.x = fmaf((bf_lo(u0) - mu0) * rs0, g.x, b.x);
        oA.y = fmaf((bf_hi(u0) - mu0) * rs0, g.y, b.y);
        oA.z = fmaf((bf_lo(u1) - mu0) * rs0, g.z, b.z);
        oA.w = fmaf((bf_hi(u1) - mu0) * rs0, g.w, b.w);
        __builtin_nontemporal_store(oA, (vfloat4*)(o0 + c * 4096 + t * 4));
        u0 = y1[c * 2 + 0]; u1 = y1[c * 2 + 1];
        vfloat4 oB;
        oB.x = fmaf((bf_lo(u0) - mu1) * rs1, g.x, b.x);
        oB.y = fmaf((bf_hi(u0) - mu1) * rs1, g.y, b.y);
        oB.z = fmaf((bf_lo(u1) - mu1) * rs1, g.z, b.z);
        oB.w = fmaf((bf_hi(u1) - mu1) * rs1, g.w, b.w);
        __builtin_nontemporal_store(oB, (vfloat4*)(o1 + c * 4096 + t * 4));
    }
}

extern "C" void kernel_launch(void* const* d_in, const int* in_sizes, int n_in,
                              void* d_out, int out_size, void* d_ws, size_t ws_size,
                              hipStream_t stream) {
    const float* x     = (const float*)d_in[0];   // [1024,1024]
    const float* scale = (const float*)d_in[1];   // [8,1024]
    const float* poly  = (const float*)d_in[2];   // [8,1024,8]
    const float* kern  = (const float*)d_in[3];   // [8,1024,8,8]
    const float* gamma = (const float*)d_in[4];   // [65536]
    const float* beta  = (const float*)d_in[5];   // [65536]
    float* out = (float*)d_out;

    // No workspace: avoids the harness's 1 GiB per-iteration ws poison-fill.
    cheb_ln_fused<<<512, 1024, 0, stream>>>(x, scale, poly, kern, gamma, beta, out);
}

// Round 3
// 373.442 us; speedup vs baseline: 1.1347x; 1.1347x over previous
//
#include <hip/hip_runtime.h>
#include <stdint.h>

// ---------------------------------------------------------------------------
// MultiHeadAdaptiveChebyshevLayer, round 5.
// R2 lessons (from counters): (a) the harness's 1 GiB workspace poison-fill
// runs UNCONDITIONALLY (165.7 us/iter) -> using the workspace is free, so
// the bf16 weight-folding prologs come back.  (b) R2's main kernel spilled
// (VGPR_Count=64, +125 MB scratch writes, VALUBusy 13%) because the compiler
// chased 2-blocks/CU occupancy; __launch_bounds__(1024, 1) lifts the VGPR
// cap to 256 so the 2-row register set (~120 live) fits spill-free.
//
// Structure: prologs fold poly into kern, pack to bf16 (W3, 1 MiB) and pack
// gamma/beta (GB3, 256 KiB).  Main: one block = TWO batch rows; every W3 /
// GB3 load and every bf16 unpack is shared between the rows.
//
// Ownership (per row): thread t owns features f = c*4096 + t*4 + {0..3},
// c = 0..15; p = c*512 + (t>>1), k = (t&1)*4 + d.
// ---------------------------------------------------------------------------

#define LN_EPS 1e-5f

typedef float vfloat4 __attribute__((ext_vector_type(4)));

__device__ __forceinline__ unsigned bf16_rne(float f) {
    unsigned u = __float_as_uint(f);
    unsigned r = u + 0x7fffu + ((u >> 16) & 1u);
    return r >> 16;
}
__device__ __forceinline__ float bf_lo(unsigned u) { return __uint_as_float(u << 16); }
__device__ __forceinline__ float bf_hi(unsigned u) { return __uint_as_float(u & 0xffff0000u); }

// Prologue 1: fold poly into kernel, bf16-pack over m, permute so the main
// kernel's load for (c,d) at lane t is W3[(c*4+d)*1024 + t].
__global__ void fold_weights_kernel(const float* __restrict__ K,
                                    const float* __restrict__ poly,
                                    uint4* __restrict__ W3) {
    int tid = blockIdx.x * blockDim.x + threadIdx.x;   // [0, 65536)
    int p = tid >> 3, k = tid & 7;
    const float* kp = K + (size_t)p * 64 + k;          // stride 8 over m
    float pw = poly[p * 8 + k];
    float v[8];
#pragma unroll
    for (int m = 0; m < 8; ++m) v[m] = kp[m * 8] * pw;
    uint4 q;
    q.x = bf16_rne(v[0]) | (bf16_rne(v[1]) << 16);
    q.y = bf16_rne(v[2]) | (bf16_rne(v[3]) << 16);
    q.z = bf16_rne(v[4]) | (bf16_rne(v[5]) << 16);
    q.w = bf16_rne(v[6]) | (bf16_rne(v[7]) << 16);
    int c = p >> 9;
    int t = ((p & 511) << 1) | (k >> 2);
    int d = k & 3;
    W3[(c * 4 + d) * 1024 + t] = q;
}

// Prologue 2: GB3[tid] covers features f = tid*4 .. +3; each word packs
// (bf16(gamma) | bf16(beta)<<16).  Main kernel reads GB3[c*1024 + t].
__global__ void pack_gb_kernel(const float* __restrict__ gamma,
                               const float* __restrict__ beta,
                               uint4* __restrict__ GB3) {
    int tid = blockIdx.x * blockDim.x + threadIdx.x;   // [0, 16384)
    float4 g = ((const float4*)gamma)[tid];
    float4 b = ((const float4*)beta)[tid];
    uint4 q;
    q.x = bf16_rne(g.x) | (bf16_rne(b.x) << 16);
    q.y = bf16_rne(g.y) | (bf16_rne(b.y) << 16);
    q.z = bf16_rne(g.z) | (bf16_rne(b.z) << 16);
    q.w = bf16_rne(g.w) | (bf16_rne(b.w) << 16);
    GB3[tid] = q;
}

// Shared-unpack dot: 8 bf16 coeffs from q feed BOTH rows' accumulators.
#define CHEB_DOT(q, accA, accB)                                               \
    {                                                                         \
        float c0 = bf_lo(q.x), c1 = bf_hi(q.x);                               \
        float c2 = bf_lo(q.y), c3 = bf_hi(q.y);                               \
        float c4 = bf_lo(q.z), c5 = bf_hi(q.z);                               \
        float c6 = bf_lo(q.w), c7 = bf_hi(q.w);                               \
        accA = fmaf(Ta1, c1, c0);   accB = fmaf(Tb1, c1, c0);                 \
        accA = fmaf(Ta2, c2, accA); accB = fmaf(Tb2, c2, accB);               \
        accA = fmaf(Ta3, c3, accA); accB = fmaf(Tb3, c3, accB);               \
        accA = fmaf(Ta4, c4, accA); accB = fmaf(Tb4, c4, accB);               \
        accA = fmaf(Ta5, c5, accA); accB = fmaf(Tb5, c5, accB);               \
        accA = fmaf(Ta6, c6, accA); accB = fmaf(Tb6, c6, accB);               \
        accA = fmaf(Ta7, c7, accA); accB = fmaf(Tb7, c7, accB);               \
    }

// Main: one block (1024 threads) per TWO batch rows.
__global__ __launch_bounds__(1024, 1) void cheb_ln_main(
    const float* __restrict__ x, const float* __restrict__ scale,
    const uint4* __restrict__ W3, const uint4* __restrict__ GB3,
    float* __restrict__ out) {
    __shared__ float xs[2][8192];
    __shared__ float red[64];
    const int r0 = blockIdx.x << 1;
    const int t = threadIdx.x;
    const int w = t >> 6, l = t & 63;
    const int phalf = t >> 1;

    // Stage xs[r][h*1024+i] = x[r][i] * scale[h][i]; scale loaded once for
    // both rows.  Coalesced; readback is 2-way same-address (free).
    float xv0 = x[(size_t)r0 * 1024 + t];
    float xv1 = x[(size_t)(r0 + 1) * 1024 + t];
#pragma unroll
    for (int h = 0; h < 8; ++h) {
        float s = scale[h * 1024 + t];
        xs[0][h * 1024 + t] = xv0 * s;
        xs[1][h * 1024 + t] = xv1 * s;
    }
    __syncthreads();

    unsigned y0[32], y1[32];         // 2 rows x 64 y-values as packed bf16
    float sum0 = 0.f, sq0 = 0.f, sum1 = 0.f, sq1 = 0.f;

#pragma unroll
    for (int c = 0; c < 16; ++c) {
        float va = xs[0][c * 512 + phalf];
        float vb = xs[1][c * 512 + phalf];
        float va2 = va + va, vb2 = vb + vb;
        float Ta1 = va, Tb1 = vb;
        float Ta2 = fmaf(va2, Ta1, -1.f),  Tb2 = fmaf(vb2, Tb1, -1.f);
        float Ta3 = fmaf(va2, Ta2, -Ta1), Tb3 = fmaf(vb2, Tb2, -Tb1);
        float Ta4 = fmaf(va2, Ta3, -Ta2), Tb4 = fmaf(vb2, Tb3, -Tb2);
        float Ta5 = fmaf(va2, Ta4, -Ta3), Tb5 = fmaf(vb2, Tb4, -Tb3);
        float Ta6 = fmaf(va2, Ta5, -Ta4), Tb6 = fmaf(vb2, Tb5, -Tb4);
        float Ta7 = fmaf(va2, Ta6, -Ta5), Tb7 = fmaf(vb2, Tb6, -Tb5);

        uint4 q0 = W3[(c * 4 + 0) * 1024 + t];  // all four: 16 B lane stride
        uint4 q1 = W3[(c * 4 + 1) * 1024 + t];
        uint4 q2 = W3[(c * 4 + 2) * 1024 + t];
        uint4 q3 = W3[(c * 4 + 3) * 1024 + t];

        float a0, a1, a2, a3, b0, b1, b2, b3;
        CHEB_DOT(q0, a0, b0);
        CHEB_DOT(q1, a1, b1);
        CHEB_DOT(q2, a2, b2);
        CHEB_DOT(q3, a3, b3);

        sum0 += (a0 + a1) + (a2 + a3);
        sq0 = fmaf(a0, a0, sq0); sq0 = fmaf(a1, a1, sq0);
        sq0 = fmaf(a2, a2, sq0); sq0 = fmaf(a3, a3, sq0);
        y0[c * 2 + 0] = bf16_rne(a0) | (bf16_rne(a1) << 16);
        y0[c * 2 + 1] = bf16_rne(a2) | (bf16_rne(a3) << 16);

        sum1 += (b0 + b1) + (b2 + b3);
        sq1 = fmaf(b0, b0, sq1); sq1 = fmaf(b1, b1, sq1);
        sq1 = fmaf(b2, b2, sq1); sq1 = fmaf(b3, b3, sq1);
        y1[c * 2 + 0] = bf16_rne(b0) | (bf16_rne(b1) << 16);
        y1[c * 2 + 1] = bf16_rne(b2) | (bf16_rne(b3) << 16);
    }

    // Wave reduce (64 lanes), then cross-wave via LDS.
#pragma unroll
    for (int off = 32; off; off >>= 1) {
        sum0 += __shfl_down(sum0, off, 64);
        sq0  += __shfl_down(sq0,  off, 64);
        sum1 += __shfl_down(sum1, off, 64);
        sq1  += __shfl_down(sq1,  off, 64);
    }
    if (l == 0) {
        red[w * 4 + 0] = sum0; red[w * 4 + 1] = sq0;
        red[w * 4 + 2] = sum1; red[w * 4 + 3] = sq1;
    }
    __syncthreads();
    float S0 = 0.f, Q0 = 0.f, S1 = 0.f, Q1 = 0.f;
#pragma unroll
    for (int q = 0; q < 16; ++q) {
        S0 += red[q * 4 + 0]; Q0 += red[q * 4 + 1];
        S1 += red[q * 4 + 2]; Q1 += red[q * 4 + 3];
    }
    const float inv = 1.f / 65536.f;
    float mu0 = S0 * inv, mu1 = S1 * inv;
    float rs0 = rsqrtf(fmaf(-mu0, mu0, Q0 * inv) + LN_EPS);
    float rs1 = rsqrtf(fmaf(-mu1, mu1, Q1 * inv) + LN_EPS);

    // Epilogue: gamma/beta loaded once, applied to both rows; NT stores.
    float* o0 = out + (size_t)r0 * 65536;
    float* o1 = o0 + 65536;
#pragma unroll
    for (int c = 0; c < 16; ++c) {
        uint4 g = GB3[c * 1024 + t];
        unsigned u0 = y0[c * 2 + 0], u1 = y0[c * 2 + 1];
        vfloat4 oA;
        oA.x = fmaf((bf_lo(u0) - mu0) * rs0, bf_lo(g.x), bf_hi(g.x));
        oA.y = fmaf((bf_hi(u0) - mu0) * rs0, bf_lo(g.y), bf_hi(g.y));
        oA.z = fmaf((bf_lo(u1) - mu0) * rs0, bf_lo(g.z), bf_hi(g.z));
        oA.w = fmaf((bf_hi(u1) - mu0) * rs0, bf_lo(g.w), bf_hi(g.w));
        __builtin_nontemporal_store(oA, (vfloat4*)(o0 + c * 4096 + t * 4));
        u0 = y1[c * 2 + 0]; u1 = y1[c * 2 + 1];
        vfloat4 oB;
        oB.x = fmaf((bf_lo(u0) - mu1) * rs1, bf_lo(g.x), bf_hi(g.x));
        oB.y = fmaf((bf_hi(u0) - mu1) * rs1, bf_lo(g.y), bf_hi(g.y));
        oB.z = fmaf((bf_lo(u1) - mu1) * rs1, bf_lo(g.z), bf_hi(g.z));
        oB.w = fmaf((bf_hi(u1) - mu1) * rs1, bf_lo(g.w), bf_hi(g.w));
        __builtin_nontemporal_store(oB, (vfloat4*)(o1 + c * 4096 + t * 4));
    }
}

extern "C" void kernel_launch(void* const* d_in, const int* in_sizes, int n_in,
                              void* d_out, int out_size, void* d_ws, size_t ws_size,
                              hipStream_t stream) {
    const float* x     = (const float*)d_in[0];   // [1024,1024]
    const float* scale = (const float*)d_in[1];   // [8,1024]
    const float* poly  = (const float*)d_in[2];   // [8,1024,8]
    const float* kern  = (const float*)d_in[3];   // [8,1024,8,8]
    const float* gamma = (const float*)d_in[4];   // [65536]
    const float* beta  = (const float*)d_in[5];   // [65536]
    float* out = (float*)d_out;

    uint4* W3  = (uint4*)d_ws;                          // 1 MiB
    uint4* GB3 = (uint4*)((char*)d_ws + (1u << 20));    // 256 KiB

    // ws poison-fill is unconditional per-iteration (R2 counters), so the
    // prologs must (and do) rebuild W3/GB3 every call — and cost nothing
    // extra vs. not using the workspace at all.
    fold_weights_kernel<<<256, 256, 0, stream>>>(kern, poly, W3);
    pack_gb_kernel<<<64, 256, 0, stream>>>(gamma, beta, GB3);
    cheb_ln_main<<<512, 1024, 0, stream>>>(x, scale, W3, GB3, out);
}

// Round 4
// 355.476 us; speedup vs baseline: 1.1920x; 1.0505x over previous
//
#include <hip/hip_runtime.h>
#include <stdint.h>

// ---------------------------------------------------------------------------
// MultiHeadAdaptiveChebyshevLayer, round 6.
// Calibrated cost model (R0/R2/R3 counters):
//   fixed tax/iter = 165.7 us (1 GiB ws poison, unconditional) + ~48 us
//   (out-poison & misc) + ~4 us prologs.  Main kernel: R0=103 us, R3=156 us.
// R3 regression root-cause: __launch_bounds__(1024,1) -> ~130 VGPR ->
//   1 block/CU (16 waves); R0's (1024,4) let the compiler hit 64 VGPR ->
//   2 blocks/CU (32 waves).  Occupancy dominates: the kernel alternates an
//   L2-latency compute phase with an HBM store burst, and only a second
//   resident block overlaps them.
// R4: R0 structure (1 row/block, 1024 blocks) with the live set dieted to
//   truly fit 64 VGPRs (W3 quads loaded 2+2 instead of 4 at once), pinned
//   via __launch_bounds__(1024, 8) => hard 64-cap, 2 blocks/CU by design.
//   LDS 33 KB/block => 2 blocks fit (66 KB < 160 KB).
//
// Ownership: thread t owns features f = c*4096 + t*4 + {0..3}, c = 0..15;
// p = c*512 + (t>>1), k = (t&1)*4 + d.
// ---------------------------------------------------------------------------

#define LN_EPS 1e-5f

typedef float vfloat4 __attribute__((ext_vector_type(4)));

__device__ __forceinline__ unsigned bf16_rne(float f) {
    unsigned u = __float_as_uint(f);
    unsigned r = u + 0x7fffu + ((u >> 16) & 1u);
    return r >> 16;
}
__device__ __forceinline__ float bf_lo(unsigned u) { return __uint_as_float(u << 16); }
__device__ __forceinline__ float bf_hi(unsigned u) { return __uint_as_float(u & 0xffff0000u); }

// Prologue 1: fold poly into kernel, bf16-pack over m, permute so the main
// kernel's load for (c,d) at lane t is W3[(c*4+d)*1024 + t].
__global__ void fold_weights_kernel(const float* __restrict__ K,
                                    const float* __restrict__ poly,
                                    uint4* __restrict__ W3) {
    int tid = blockIdx.x * blockDim.x + threadIdx.x;   // [0, 65536)
    int p = tid >> 3, k = tid & 7;
    const float* kp = K + (size_t)p * 64 + k;          // stride 8 over m
    float pw = poly[p * 8 + k];
    float v[8];
#pragma unroll
    for (int m = 0; m < 8; ++m) v[m] = kp[m * 8] * pw;
    uint4 q;
    q.x = bf16_rne(v[0]) | (bf16_rne(v[1]) << 16);
    q.y = bf16_rne(v[2]) | (bf16_rne(v[3]) << 16);
    q.z = bf16_rne(v[4]) | (bf16_rne(v[5]) << 16);
    q.w = bf16_rne(v[6]) | (bf16_rne(v[7]) << 16);
    int c = p >> 9;
    int t = ((p & 511) << 1) | (k >> 2);
    int d = k & 3;
    W3[(c * 4 + d) * 1024 + t] = q;
}

// Prologue 2: GB3[tid] covers features f = tid*4 .. +3; each word packs
// (bf16(gamma) | bf16(beta)<<16).  Main kernel reads GB3[c*1024 + t].
__global__ void pack_gb_kernel(const float* __restrict__ gamma,
                               const float* __restrict__ beta,
                               uint4* __restrict__ GB3) {
    int tid = blockIdx.x * blockDim.x + threadIdx.x;   // [0, 16384)
    float4 g = ((const float4*)gamma)[tid];
    float4 b = ((const float4*)beta)[tid];
    uint4 q;
    q.x = bf16_rne(g.x) | (bf16_rne(b.x) << 16);
    q.y = bf16_rne(g.y) | (bf16_rne(b.y) << 16);
    q.z = bf16_rne(g.z) | (bf16_rne(b.z) << 16);
    q.w = bf16_rne(g.w) | (bf16_rne(b.w) << 16);
    GB3[tid] = q;
}

// 8-term Chebyshev dot against one packed-bf16 quad (T1..T7 in scope).
#define CHEB_DOT(q, acc)                                                      \
    {                                                                         \
        float c0 = bf_lo(q.x), c1 = bf_hi(q.x);                               \
        float c2 = bf_lo(q.y), c3 = bf_hi(q.y);                               \
        float c4 = bf_lo(q.z), c5 = bf_hi(q.z);                               \
        float c6 = bf_lo(q.w), c7 = bf_hi(q.w);                               \
        acc = fmaf(T1, c1, c0);                                               \
        acc = fmaf(T2, c2, acc);                                              \
        acc = fmaf(T3, c3, acc);                                              \
        acc = fmaf(T4, c4, acc);                                              \
        acc = fmaf(T5, c5, acc);                                              \
        acc = fmaf(T6, c6, acc);                                              \
        acc = fmaf(T7, c7, acc);                                              \
    }

// Main: one block (1024 threads) per batch row; 2 blocks/CU by construction.
__global__ __launch_bounds__(1024, 8) void cheb_ln_main(
    const float* __restrict__ x, const float* __restrict__ scale,
    const uint4* __restrict__ W3, const uint4* __restrict__ GB3,
    float* __restrict__ out) {
    __shared__ float xs[8192];
    __shared__ float red[32];
    const int r = blockIdx.x;
    const int t = threadIdx.x;
    const int w = t >> 6, l = t & 63;
    const int phalf = t >> 1;

    // Stage xs[h*1024 + i] = x[i] * scale[h*1024 + i] (coalesced; x loaded
    // once, reused across 8 heads).
    float xv = x[(size_t)r * 1024 + t];
#pragma unroll
    for (int h = 0; h < 8; ++h)
        xs[h * 1024 + t] = xv * scale[h * 1024 + t];
    __syncthreads();

    unsigned y2[32];            // 64 y values as packed bf16 pairs
    float sum = 0.f, sq = 0.f;

#pragma unroll
    for (int c = 0; c < 16; ++c) {
        float v = xs[c * 512 + phalf];          // 2-way broadcast, no conflicts
        float v2 = v + v;
        float T1 = v;
        float T2 = fmaf(v2, T1, -1.f);
        float T3 = fmaf(v2, T2, -T1);
        float T4 = fmaf(v2, T3, -T2);
        float T5 = fmaf(v2, T4, -T3);
        float T6 = fmaf(v2, T5, -T4);
        float T7 = fmaf(v2, T6, -T5);

        // Quads loaded 2-at-a-time: peak liveness ~58 regs -> fits the
        // 64-VGPR budget (8 waves/EU) without spilling.
        float a0, a1, a2, a3;
        {
            uint4 q0 = W3[(c * 4 + 0) * 1024 + t];
            uint4 q1 = W3[(c * 4 + 1) * 1024 + t];
            CHEB_DOT(q0, a0);
            CHEB_DOT(q1, a1);
        }
        {
            uint4 q2 = W3[(c * 4 + 2) * 1024 + t];
            uint4 q3 = W3[(c * 4 + 3) * 1024 + t];
            CHEB_DOT(q2, a2);
            CHEB_DOT(q3, a3);
        }

        sum += (a0 + a1) + (a2 + a3);
        sq = fmaf(a0, a0, sq); sq = fmaf(a1, a1, sq);
        sq = fmaf(a2, a2, sq); sq = fmaf(a3, a3, sq);
        y2[c * 2 + 0] = bf16_rne(a0) | (bf16_rne(a1) << 16);
        y2[c * 2 + 1] = bf16_rne(a2) | (bf16_rne(a3) << 16);
    }

    // Wave reduce (64 lanes), then cross-wave via LDS.
#pragma unroll
    for (int off = 32; off; off >>= 1) {
        sum += __shfl_down(sum, off, 64);
        sq  += __shfl_down(sq,  off, 64);
    }
    if (l == 0) { red[w] = sum; red[w + 16] = sq; }
    __syncthreads();
    float S = 0.f, SQ = 0.f;
#pragma unroll
    for (int q = 0; q < 16; ++q) { S += red[q]; SQ += red[q + 16]; }
    const float inv = 1.f / 65536.f;
    float mu = S * inv;
    float var = fmaf(-mu, mu, SQ * inv);
    float rstd = rsqrtf(var + LN_EPS);

    // Epilogue: unpack y, normalize, affine, nontemporal coalesced stores.
    float* orow = out + (size_t)r * 65536;
#pragma unroll
    for (int c = 0; c < 16; ++c) {
        uint4 g = GB3[c * 1024 + t];
        unsigned u0 = y2[c * 2 + 0], u1 = y2[c * 2 + 1];
        vfloat4 o;
        o.x = fmaf((bf_lo(u0) - mu) * rstd, bf_lo(g.x), bf_hi(g.x));
        o.y = fmaf((bf_hi(u0) - mu) * rstd, bf_lo(g.y), bf_hi(g.y));
        o.z = fmaf((bf_lo(u1) - mu) * rstd, bf_lo(g.z), bf_hi(g.z));
        o.w = fmaf((bf_hi(u1) - mu) * rstd, bf_lo(g.w), bf_hi(g.w));
        __builtin_nontemporal_store(o, (vfloat4*)(orow + c * 4096 + t * 4));
    }
}

extern "C" void kernel_launch(void* const* d_in, const int* in_sizes, int n_in,
                              void* d_out, int out_size, void* d_ws, size_t ws_size,
                              hipStream_t stream) {
    const float* x     = (const float*)d_in[0];   // [1024,1024]
    const float* scale = (const float*)d_in[1];   // [8,1024]
    const float* poly  = (const float*)d_in[2];   // [8,1024,8]
    const float* kern  = (const float*)d_in[3];   // [8,1024,8,8]
    const float* gamma = (const float*)d_in[4];   // [65536]
    const float* beta  = (const float*)d_in[5];   // [65536]
    float* out = (float*)d_out;

    uint4* W3  = (uint4*)d_ws;                          // 1 MiB
    uint4* GB3 = (uint4*)((char*)d_ws + (1u << 20));    // 256 KiB

    fold_weights_kernel<<<256, 256, 0, stream>>>(kern, poly, W3);
    pack_gb_kernel<<<64, 256, 0, stream>>>(gamma, beta, GB3);
    cheb_ln_main<<<1024, 1024, 0, stream>>>(x, scale, W3, GB3, out);
}